// Round 1
// baseline (4025.484 us; speedup 1.0000x reference)
//
#include <hip/hip_runtime.h>

#define BB 16
#define NN 64
#define SS 4096
#define CC 768
#define HH 8
#define HD 96

// ---------------------------------------------------------------------------
// K1: q = query @ Wq^T (fp64), then qk[b,h,n,c] = SCALE * sum_d q_d * Wk[h*96+d, c]
// 4 (b,n) rows per block. Writes fp64 (exact rescore path) + fp32 (filter path).
// ---------------------------------------------------------------------------
__global__ __launch_bounds__(256) void k_qkfold(
    const float* __restrict__ query, const float* __restrict__ Wq,
    const float* __restrict__ Wk, double* __restrict__ qk64,
    float* __restrict__ qk32) {
  __shared__ float qin[4][CC];
  __shared__ double q64[4][CC];
  const int tid = threadIdx.x;
  const int r0 = blockIdx.x * 4;  // linear (b*64+n) row base

  for (int u = 0; u < 12; ++u) {
    int idx = tid + u * 256;
    int r = idx / CC, c = idx - r * CC;
    qin[r][c] = query[(size_t)(r0 + r) * CC + c];
  }
  __syncthreads();

  for (int jj = 0; jj < 3; ++jj) {
    int j = tid + jj * 256;
    double a0 = 0.0, a1 = 0.0, a2 = 0.0, a3 = 0.0;
    const float* wrow = Wq + (size_t)j * CC;
#pragma unroll 4
    for (int e = 0; e < CC; ++e) {
      double w = (double)wrow[e];
      a0 += w * (double)qin[0][e];
      a1 += w * (double)qin[1][e];
      a2 += w * (double)qin[2][e];
      a3 += w * (double)qin[3][e];
    }
    q64[0][j] = a0; q64[1][j] = a1; q64[2][j] = a2; q64[3][j] = a3;
  }
  __syncthreads();

  const double SC = 0.10206207261596575;  // 96^-0.5
  for (int h = 0; h < HH; ++h) {
    for (int cc = 0; cc < 3; ++cc) {
      int c = tid + cc * 256;
      double a0 = 0.0, a1 = 0.0, a2 = 0.0, a3 = 0.0;
#pragma unroll 4
      for (int dd = 0; dd < HD; ++dd) {
        double w = (double)Wk[(size_t)(h * HD + dd) * CC + c];
        double q0 = q64[0][h * HD + dd];
        double q1 = q64[1][h * HD + dd];
        double q2 = q64[2][h * HD + dd];
        double q3 = q64[3][h * HD + dd];
        a0 += q0 * w; a1 += q1 * w; a2 += q2 * w; a3 += q3 * w;
      }
      a0 *= SC; a1 *= SC; a2 *= SC; a3 *= SC;
      {
        int row = r0 + 0, b = row >> 6, n = row & 63;
        size_t o = ((size_t)(b * HH + h) * NN + n) * CC + c;
        qk64[o] = a0; qk32[o] = (float)a0;
      }
      {
        int row = r0 + 1, b = row >> 6, n = row & 63;
        size_t o = ((size_t)(b * HH + h) * NN + n) * CC + c;
        qk64[o] = a1; qk32[o] = (float)a1;
      }
      {
        int row = r0 + 2, b = row >> 6, n = row & 63;
        size_t o = ((size_t)(b * HH + h) * NN + n) * CC + c;
        qk64[o] = a2; qk32[o] = (float)a2;
      }
      {
        int row = r0 + 3, b = row >> 6, n = row & 63;
        size_t o = ((size_t)(b * HH + h) * NN + n) * CC + c;
        qk64[o] = a3; qk32[o] = (float)a3;
      }
    }
  }
}

// ---------------------------------------------------------------------------
// K2: fp32 logits + argmax filter. Block = (b, h, 128-token tile).
// Thread owns 4 tokens x 8 groups. Key tile in LDS (stride 132 pad),
// qk32 streamed from L1/L2. Tokens with top-2 gap < DELTA get queued
// for exact fp64 rescore. Worst-case fp32 dot error ~1.5e-4 << DELTA.
// ---------------------------------------------------------------------------
#define DELTA 1e-3f

__global__ __launch_bounds__(256) void k_filter(
    const float* __restrict__ key, const float* __restrict__ qk32,
    unsigned char* __restrict__ assign, int* __restrict__ susp,
    int* __restrict__ scnt) {
  __shared__ float klds[128 * 132];
  const int tid = threadIdx.x;
  const int bid = blockIdx.x;          // 16*8*32 = 4096
  const int stile = bid & 31;
  const int h = (bid >> 5) & 7;
  const int b = bid >> 8;
  const int s0 = stile * 128;
  const int tokq = tid >> 3;           // 0..31 -> tokens tokq*4..+3
  const int parth = tid & 7;           // 0..7  -> groups parth*8..+7

  float acc[4][8];
#pragma unroll
  for (int i = 0; i < 4; ++i)
#pragma unroll
    for (int j = 0; j < 8; ++j) acc[i][j] = 0.0f;

  const float* qkbase = qk32 + ((size_t)(b * HH + h) * NN + parth * 8) * CC;

  for (int cc = 0; cc < 6; ++cc) {
    const int c0 = cc * 128;
#pragma unroll
    for (int u = 0; u < 16; ++u) {
      int idx4 = tid + u * 256;        // 0..4095
      int r = idx4 >> 5;               // 0..127
      int q4 = idx4 & 31;
      float4 v = *(const float4*)(key + ((size_t)(b * SS + s0 + r)) * CC + c0 + q4 * 4);
      *(float4*)(klds + r * 132 + q4 * 4) = v;
    }
    __syncthreads();

    const float* qc = qkbase + c0;
    for (int c4 = 0; c4 < 32; ++c4) {
      const float4 k0 = *(const float4*)(klds + (tokq * 4 + 0) * 132 + c4 * 4);
      const float4 k1 = *(const float4*)(klds + (tokq * 4 + 1) * 132 + c4 * 4);
      const float4 k2 = *(const float4*)(klds + (tokq * 4 + 2) * 132 + c4 * 4);
      const float4 k3 = *(const float4*)(klds + (tokq * 4 + 3) * 132 + c4 * 4);
#pragma unroll
      for (int j = 0; j < 8; ++j) {
        const float4 qv = *(const float4*)(qc + (size_t)j * CC + c4 * 4);
        acc[0][j] = fmaf(k0.x, qv.x, acc[0][j]);
        acc[0][j] = fmaf(k0.y, qv.y, acc[0][j]);
        acc[0][j] = fmaf(k0.z, qv.z, acc[0][j]);
        acc[0][j] = fmaf(k0.w, qv.w, acc[0][j]);
        acc[1][j] = fmaf(k1.x, qv.x, acc[1][j]);
        acc[1][j] = fmaf(k1.y, qv.y, acc[1][j]);
        acc[1][j] = fmaf(k1.z, qv.z, acc[1][j]);
        acc[1][j] = fmaf(k1.w, qv.w, acc[1][j]);
        acc[2][j] = fmaf(k2.x, qv.x, acc[2][j]);
        acc[2][j] = fmaf(k2.y, qv.y, acc[2][j]);
        acc[2][j] = fmaf(k2.z, qv.z, acc[2][j]);
        acc[2][j] = fmaf(k2.w, qv.w, acc[2][j]);
        acc[3][j] = fmaf(k3.x, qv.x, acc[3][j]);
        acc[3][j] = fmaf(k3.y, qv.y, acc[3][j]);
        acc[3][j] = fmaf(k3.z, qv.z, acc[3][j]);
        acc[3][j] = fmaf(k3.w, qv.w, acc[3][j]);
      }
    }
    __syncthreads();
  }

#pragma unroll
  for (int i = 0; i < 4; ++i) {
    float m1 = -3.402823466e38f, m2 = -3.402823466e38f;
    int i1 = 0;
#pragma unroll
    for (int j = 0; j < 8; ++j) {
      float v = acc[i][j];
      int n = parth * 8 + j;
      if (v > m1) { m2 = m1; m1 = v; i1 = n; }
      else if (v > m2) m2 = v;
    }
#pragma unroll
    for (int off = 1; off <= 4; off <<= 1) {
      float om1 = __shfl_xor(m1, off);
      float om2 = __shfl_xor(m2, off);
      int oi1 = __shfl_xor(i1, off);
      if (om1 > m1 || (om1 == m1 && oi1 < i1)) {
        m2 = fmaxf(m1, fmaxf(m2, om2));
        m1 = om1; i1 = oi1;
      } else {
        m2 = fmaxf(om1, fmaxf(m2, om2));
      }
    }
    if (parth == 0) {
      int s = s0 + tokq * 4 + i;
      int bh = b * HH + h;
      assign[(size_t)bh * SS + s] = (unsigned char)i1;
      if (m1 - m2 < DELTA) {
        int w = atomicAdd(scnt, 1);
        susp[w] = (bh << 12) | s;
      }
    }
  }
}

// ---------------------------------------------------------------------------
// K3: exact fp64 rescore of suspicious tokens; first-index tie-break.
// ---------------------------------------------------------------------------
__global__ __launch_bounds__(256) void k_rescore(
    const float* __restrict__ key, const double* __restrict__ qk64,
    const int* __restrict__ susp, const int* __restrict__ scnt,
    unsigned char* __restrict__ assign) {
  __shared__ double l64[64];
  const int cnt = *scnt;
  const int n = threadIdx.x >> 2;
  const int q = threadIdx.x & 3;
  for (int ii = blockIdx.x; ii < cnt; ii += gridDim.x) {
    int pk = susp[ii];
    int bh = pk >> 12;
    int s = pk & 4095;
    const float* krow = key + ((size_t)(bh >> 3) * SS + s) * CC;
    const double* qrow = qk64 + ((size_t)bh * NN + n) * CC;
    double a = 0.0;
    for (int c = q * 192; c < q * 192 + 192; ++c)
      a += (double)krow[c] * qrow[c];
    a += __shfl_xor(a, 1);
    a += __shfl_xor(a, 2);
    if (q == 0) l64[n] = a;
    __syncthreads();
    if (threadIdx.x == 0) {
      double best = l64[0];
      int bi = 0;
      for (int n2 = 1; n2 < 64; ++n2)
        if (l64[n2] > best) { best = l64[n2]; bi = n2; }
      assign[(size_t)bh * SS + s] = (unsigned char)bi;
    }
    __syncthreads();
  }
}

// ---------------------------------------------------------------------------
// K4: deterministic group gather: gsnorm[b,h,n,c] =
//     (sum_{s: assign=n} key[b,s,c]) / (count+1).  Block per (b,h,n);
//     4 waves each scan 1024 tokens; wave-uniform branch.
// ---------------------------------------------------------------------------
__global__ __launch_bounds__(256) void k_gather(
    const float* __restrict__ key, const unsigned char* __restrict__ assign,
    float* __restrict__ gsnorm) {
  __shared__ unsigned int alds_u[SS / 4];
  __shared__ float psum[4][CC];
  __shared__ int pcnt[4];
  const unsigned char* alds = (const unsigned char*)alds_u;
  const int bid = blockIdx.x;          // ((b*8+h)*64 + n)
  const int n = bid & 63;
  const int bh = bid >> 6;
  const int b = bh >> 3;
  const int tid = threadIdx.x;

  const unsigned int* arow = (const unsigned int*)(assign + (size_t)bh * SS);
  for (int u = 0; u < 4; ++u) alds_u[tid + u * 256] = arow[tid + u * 256];
  __syncthreads();

  const int w = tid >> 6, l = tid & 63;
  float acc[12];
#pragma unroll
  for (int k = 0; k < 12; ++k) acc[k] = 0.0f;
  int cnt = 0;
  const float* kb = key + (size_t)b * SS * CC;
  for (int ss = 0; ss < 1024; ++ss) {
    int s = w * 1024 + ss;
    if (alds[s] == n) {
      ++cnt;
      const float* kr = kb + (size_t)s * CC + l;
#pragma unroll
      for (int k = 0; k < 12; ++k) acc[k] += kr[k * 64];
    }
  }
#pragma unroll
  for (int k = 0; k < 12; ++k) psum[w][l + 64 * k] = acc[k];
  if (l == 0) pcnt[w] = cnt;
  __syncthreads();
  for (int m = 0; m < 3; ++m) {
    int c = tid + m * 256;
    float t = psum[0][c] + psum[1][c] + psum[2][c] + psum[3][c];
    int tot = pcnt[0] + pcnt[1] + pcnt[2] + pcnt[3];
    gsnorm[(size_t)bid * CC + c] = t / (float)(tot + 1);
  }
}

// ---------------------------------------------------------------------------
// K5: fused Wv projection + Wo projection + bias. 4 (b,n) rows per block.
// ---------------------------------------------------------------------------
__global__ __launch_bounds__(256) void k_out(
    const float* __restrict__ gsnorm, const float* __restrict__ Wv,
    const float* __restrict__ Wo, const float* __restrict__ bo,
    float* __restrict__ out) {
  __shared__ float gs[4][HH][CC];
  __shared__ float vr[4][CC];
  const int tid = threadIdx.x;
  const int r0 = blockIdx.x * 4;

  for (int r = 0; r < 4; ++r) {
    int row = r0 + r, b = row >> 6, n = row & 63;
    for (int h = 0; h < HH; ++h) {
      const float* src = gsnorm + ((size_t)(b * HH + h) * NN + n) * CC;
      for (int m = 0; m < 3; ++m) gs[r][h][tid + m * 256] = src[tid + m * 256];
    }
  }
  __syncthreads();

  for (int m = 0; m < 3; ++m) {
    int j = tid + m * 256;
    int hh = j / HD;
    float a0 = 0.f, a1 = 0.f, a2 = 0.f, a3 = 0.f;
    const float* wrow = Wv + (size_t)j * CC;
#pragma unroll 4
    for (int c = 0; c < CC; ++c) {
      float wv = wrow[c];
      a0 = fmaf(gs[0][hh][c], wv, a0);
      a1 = fmaf(gs[1][hh][c], wv, a1);
      a2 = fmaf(gs[2][hh][c], wv, a2);
      a3 = fmaf(gs[3][hh][c], wv, a3);
    }
    vr[0][j] = a0; vr[1][j] = a1; vr[2][j] = a2; vr[3][j] = a3;
  }
  __syncthreads();

  for (int m = 0; m < 3; ++m) {
    int j = tid + m * 256;
    float bb = bo[j];
    float a0 = bb, a1 = bb, a2 = bb, a3 = bb;
    const float* wrow = Wo + (size_t)j * CC;
#pragma unroll 4
    for (int c = 0; c < CC; ++c) {
      float wv = wrow[c];
      a0 = fmaf(vr[0][c], wv, a0);
      a1 = fmaf(vr[1][c], wv, a1);
      a2 = fmaf(vr[2][c], wv, a2);
      a3 = fmaf(vr[3][c], wv, a3);
    }
    out[(size_t)(r0 + 0) * CC + j] = a0;
    out[(size_t)(r0 + 1) * CC + j] = a1;
    out[(size_t)(r0 + 2) * CC + j] = a2;
    out[(size_t)(r0 + 3) * CC + j] = a3;
  }
}

// ---------------------------------------------------------------------------
extern "C" void kernel_launch(void* const* d_in, const int* in_sizes, int n_in,
                              void* d_out, int out_size, void* d_ws, size_t ws_size,
                              hipStream_t stream) {
  const float* query = (const float*)d_in[0];
  const float* key   = (const float*)d_in[1];
  const float* Wq    = (const float*)d_in[2];
  const float* Wk    = (const float*)d_in[3];
  const float* Wv    = (const float*)d_in[4];
  const float* Wo    = (const float*)d_in[5];
  const float* bo    = (const float*)d_in[6];
  float* out = (float*)d_out;

  char* ws = (char*)d_ws;
  // layout (bytes):
  double* qk64          = (double*)(ws);                    // 8192*768*8  = 50331648
  float* qk32           = (float*)(ws + 50331648);          // 8192*768*4  = 25165824
  float* gsnorm         = (float*)(ws + 75497472);          // 8192*768*4  = 25165824
  unsigned char* assign = (unsigned char*)(ws + 100663296); // 524288
  int* susp             = (int*)(ws + 101187584);           // 524288*4 = 2097152
  int* scnt             = (int*)(ws + 103284736);           // 4

  hipMemsetAsync(scnt, 0, 4, stream);
  k_qkfold<<<256, 256, 0, stream>>>(query, Wq, Wk, qk64, qk32);
  k_filter<<<4096, 256, 0, stream>>>(key, qk32, assign, susp, scnt);
  k_rescore<<<512, 256, 0, stream>>>(key, qk64, susp, scnt, assign);
  k_gather<<<8192, 256, 0, stream>>>(key, assign, gsnorm);
  k_out<<<256, 256, 0, stream>>>(gsnorm, Wv, Wo, bo, out);
}